// Round 1
// baseline (520.311 us; speedup 1.0000x reference)
//
#include <hip/hip_runtime.h>

typedef unsigned short u16;
typedef unsigned int u32;
typedef __bf16 bf16x8 __attribute__((ext_vector_type(8)));
typedef float f32x4 __attribute__((ext_vector_type(4)));

#define DI __device__ __forceinline__

DI u16 f2bf(float f) {
  union { float f; u32 u; } v; v.f = f;
  u32 r = (v.u + 0x7fffu + ((v.u >> 16) & 1u)) >> 16;
  return (u16)r;
}
DI float bf2f(u16 h) {
  union { u32 u; float f; } v; v.u = ((u32)h) << 16;
  return v.f;
}

constexpr float INV_M = 1.0f / 32768.0f;  // 1/(B*C) = 1/(64*512)

// ---------------- weight convert/pack: [WA,WB,WU,WV,WE] x 2 layers -> bf16 ----------------
__global__ void convw_k(const float* wa1, const float* wb1, const float* wu1, const float* wv1, const float* we1,
                        const float* wa2, const float* wb2, const float* wu2, const float* wv2, const float* we2,
                        u16* dst) {
  int idx = blockIdx.x * 256 + threadIdx.x;
  int m = idx >> 18;          // 512*512 = 2^18 per matrix
  int i = idx & 0x3ffff;
  const float* s;
  switch (m) {
    case 0: s = wa1; break; case 1: s = wb1; break; case 2: s = wu1; break;
    case 3: s = wv1; break; case 4: s = we1; break; case 5: s = wa2; break;
    case 6: s = wb2; break; case 7: s = wu2; break; case 8: s = wv2; break;
    default: s = we2; break;
  }
  dst[idx] = f2bf(s[i]);
}

// ---------------- GEMM: out[m,n] = sum_k A[m,k] * W[n,k]  (A fp32, W bf16) ----------------
// BM=64, BN=256, BK=64, 256 threads (4 waves, 2x2), wave tile 32x128.
// EPI==1: plain fp32 store to outf (ld = ldout).    (x-GEMM -> V4 [1728,2048])
// EPI==2: msg = acc + Vix + Vjx, store bf16, fused per-edge sum/sumsq atomics. (edge GEMM)
template<int EPI>
__global__ __launch_bounds__(256, 3) void gemm_k(
    const float* __restrict__ A, const u16* __restrict__ W,
    float* __restrict__ outf, int ldout,
    u16* __restrict__ msg, const float* __restrict__ V4,
    float* __restrict__ esum, float* __restrict__ esq) {
  __shared__ __align__(16) u16 lA[64 * 72];    // 64 rows, 64 data + 8 pad bf16
  __shared__ __align__(16) u16 lW[256 * 72];
  const int tid = threadIdx.x;
  const int lane = tid & 63, wid = tid >> 6;
  const int wm = wid >> 1, wn = wid & 1;
  const int q = lane >> 4, l15 = lane & 15;
  const int rb = blockIdx.y, cb = blockIdx.x;

  f32x4 acc[2][8];
#pragma unroll
  for (int a = 0; a < 2; a++)
#pragma unroll
    for (int b = 0; b < 8; b++) acc[a][b] = (f32x4){0.f, 0.f, 0.f, 0.f};

  for (int k0 = 0; k0 < 512; k0 += 64) {
    __syncthreads();
    // stage A (fp32 -> bf16): 64 rows x 8 granules(16B)
#pragma unroll
    for (int t = tid; t < 512; t += 256) {
      int row = t >> 3, g = t & 7;
      const float* src = A + (((size_t)(rb * 64 + row)) << 9) + k0 + g * 8;
      float4 s0 = *(const float4*)src;
      float4 s1 = *(const float4*)(src + 4);
      uint4 p;
      p.x = f2bf(s0.x) | ((u32)f2bf(s0.y) << 16);
      p.y = f2bf(s0.z) | ((u32)f2bf(s0.w) << 16);
      p.z = f2bf(s1.x) | ((u32)f2bf(s1.y) << 16);
      p.w = f2bf(s1.z) | ((u32)f2bf(s1.w) << 16);
      *(uint4*)(lA + row * 72 + g * 8) = p;
    }
    // stage W (bf16): 256 rows x 8 granules
#pragma unroll
    for (int t = tid; t < 2048; t += 256) {
      int row = t >> 3, g = t & 7;
      const u16* src = W + (((size_t)(cb * 256 + row)) << 9) + k0 + g * 8;
      *(uint4*)(lW + row * 72 + g * 8) = *(const uint4*)src;
    }
    __syncthreads();
#pragma unroll
    for (int ks = 0; ks < 2; ks++) {
      const int ko = ks * 32 + q * 8;
      bf16x8 af[2], wf[8];
#pragma unroll
      for (int mt = 0; mt < 2; mt++)
        af[mt] = *(const bf16x8*)(lA + (wm * 32 + mt * 16 + l15) * 72 + ko);
#pragma unroll
      for (int nt = 0; nt < 8; nt++)
        wf[nt] = *(const bf16x8*)(lW + (wn * 128 + nt * 16 + l15) * 72 + ko);
#pragma unroll
      for (int mt = 0; mt < 2; mt++)
#pragma unroll
        for (int nt = 0; nt < 8; nt++)
          acc[mt][nt] = __builtin_amdgcn_mfma_f32_16x16x32_bf16(af[mt], wf[nt], acc[mt][nt], 0, 0, 0);
    }
  }

  if (EPI == 1) {
#pragma unroll
    for (int mt = 0; mt < 2; mt++) {
      int grow0 = rb * 64 + wm * 32 + mt * 16 + q * 4;
#pragma unroll
      for (int nt = 0; nt < 8; nt++) {
        int gcol = cb * 256 + wn * 128 + nt * 16 + l15;
#pragma unroll
        for (int r = 0; r < 4; r++)
          outf[(size_t)(grow0 + r) * ldout + gcol] = acc[mt][nt][r];
      }
    }
  } else {
    // msg = elin + Vix[b,i,:] + Vjx[b,j,:]; row = b*729 + i*27 + j
    float ms[2][4], m2[2][4];
#pragma unroll
    for (int mt = 0; mt < 2; mt++) {
#pragma unroll
      for (int r = 0; r < 4; r++) {
        int grow = rb * 64 + wm * 32 + mt * 16 + q * 4 + r;
        int b = grow / 729;
        int e = grow - b * 729;
        int i = e / 27;
        int j = e - i * 27;
        const float* vix = V4 + (((size_t)(b * 27 + i)) << 11);
        const float* vjx = V4 + (((size_t)(b * 27 + j)) << 11) + 512;
        u16* mrow = msg + (((size_t)grow) << 9);
        float s1 = 0.f, s2 = 0.f;
#pragma unroll
        for (int nt = 0; nt < 8; nt++) {
          int c = cb * 256 + wn * 128 + nt * 16 + l15;
          float m = acc[mt][nt][r] + vix[c] + vjx[c];
          mrow[c] = f2bf(m);
          s1 += m;
          s2 += m * m;
        }
        ms[mt][r] = s1;
        m2[mt][r] = s2;
      }
    }
    // reduce across the 16 lanes of each quad (cols)
#pragma unroll
    for (int msk = 1; msk < 16; msk <<= 1) {
#pragma unroll
      for (int mt = 0; mt < 2; mt++)
#pragma unroll
        for (int r = 0; r < 4; r++) {
          ms[mt][r] += __shfl_xor(ms[mt][r], msk);
          m2[mt][r] += __shfl_xor(m2[mt][r], msk);
        }
    }
    __syncthreads();
    float* sm = (float*)lA;  // reuse LDS: [wn*64+row] sums, +128 sumsq
    if (l15 == 0) {
#pragma unroll
      for (int mt = 0; mt < 2; mt++)
#pragma unroll
        for (int r = 0; r < 4; r++) {
          int rib = wm * 32 + mt * 16 + q * 4 + r;
          sm[wn * 64 + rib] = ms[mt][r];
          sm[128 + wn * 64 + rib] = m2[mt][r];
        }
    }
    __syncthreads();
    if (tid < 64) {
      int grow = rb * 64 + tid;
      int e = grow % 729;
      atomicAdd(&esum[e], sm[tid] + sm[64 + tid]);
      atomicAdd(&esq[e], sm[128 + tid] + sm[192 + tid]);
    }
  }
}

// ---------------- finalize edge BN stats -> per-edge (a,b): bn(x) = a*x + b ----------------
__global__ void eab_fin_k(const float* __restrict__ sum, const float* __restrict__ sq,
                          const float* __restrict__ g, const float* __restrict__ bt,
                          float2* __restrict__ ab, int n) {
  int i = blockIdx.x * 256 + threadIdx.x;
  if (i >= n) return;
  float mean = sum[i] * INV_M;
  float var = sq[i] * INV_M - mean * mean;
  float rs = rsqrtf(var + 1e-5f);
  float a = g[i] * rs;
  ab[i] = make_float2(a, bt[i] - mean * a);
}

// ---------------- fused: edge-out = ein + relu(bn(msg)); sigmoid+softmax_j; agg; xnew; vstats ----------------
__global__ __launch_bounds__(512) void edge_attn_k(
    const u16* __restrict__ msg, const float* __restrict__ ein, float* __restrict__ eout,
    const float2* __restrict__ eab, const float* __restrict__ V4,
    float* __restrict__ xnew, float* __restrict__ vsum, float* __restrict__ vsq) {
  const int bi = blockIdx.x;          // b*27 + i
  const int b = bi / 27, i = bi - b * 27;
  const int c = threadIdx.x;
  const size_t ebase = (((size_t)b * 729 + i * 27) << 9) + c;
  float texp[27];
  float ssum = 0.f;
#pragma unroll
  for (int j = 0; j < 27; j++) {
    size_t idx = ebase + (((size_t)j) << 9);
    float2 ab = eab[i * 27 + j];
    float bn = fmaf(ab.x, bf2f(msg[idx]), ab.y);
    float eo = ein[idx] + fmaxf(bn, 0.f);
    eout[idx] = eo;
    float s = 1.f / (1.f + __expf(-eo));
    float t = __expf(s);
    ssum += t;
    texp[j] = t;
  }
  float accv = 0.f;
#pragma unroll
  for (int j = 0; j < 27; j++)
    accv = fmaf(texp[j], V4[(((size_t)(b * 27 + j)) << 11) + 1536 + c], accv);  // Ujx
  float xn = V4[(((size_t)(b * 27 + i)) << 11) + 1024 + c] + accv / (ssum * 27.f);  // Uix + agg/N
  xnew[(((size_t)bi) << 9) + c] = xn;
  // vertex BN partial stats
  float v = xn, v2 = xn * xn;
#pragma unroll
  for (int m = 32; m >= 1; m >>= 1) {
    v += __shfl_xor(v, m);
    v2 += __shfl_xor(v2, m);
  }
  __shared__ float red[16];
  int w = threadIdx.x >> 6, ln = threadIdx.x & 63;
  if (ln == 0) { red[w] = v; red[8 + w] = v2; }
  __syncthreads();
  if (threadIdx.x == 0) {
    float s1 = 0.f, s2 = 0.f;
#pragma unroll
    for (int k = 0; k < 8; k++) { s1 += red[k]; s2 += red[8 + k]; }
    atomicAdd(&vsum[i], s1);
    atomicAdd(&vsq[i], s2);
  }
}

// ---------------- x_out = relu(res + bn_v(xnew)) ----------------
__global__ void vert_bn_k(const float* __restrict__ xnew, const float* __restrict__ res,
                          const float* __restrict__ vsum, const float* __restrict__ vsq,
                          const float* __restrict__ g, const float* __restrict__ bt,
                          float* __restrict__ out) {
  int idx = blockIdx.x * 256 + threadIdx.x;
  int i = (idx >> 9) % 27;
  float mean = vsum[i] * INV_M;
  float var = vsq[i] * INV_M - mean * mean;
  float rs = rsqrtf(var + 1e-5f);
  float a = g[i] * rs;
  float bb = bt[i] - mean * a;
  out[idx] = fmaxf(res[idx] + fmaf(a, xnew[idx], bb), 0.f);
}

extern "C" void kernel_launch(void* const* d_in, const int* in_sizes, int n_in,
                              void* d_out, int out_size, void* d_ws, size_t ws_size,
                              hipStream_t stream) {
  const float* x    = (const float*)d_in[0];
  const float* edge = (const float*)d_in[1];
  const float* WU1 = (const float*)d_in[2];
  const float* WV1 = (const float*)d_in[3];
  const float* WA1 = (const float*)d_in[4];
  const float* WB1 = (const float*)d_in[5];
  const float* WE1 = (const float*)d_in[6];
  const float* WU2 = (const float*)d_in[7];
  const float* WV2 = (const float*)d_in[8];
  const float* WA2 = (const float*)d_in[9];
  const float* WB2 = (const float*)d_in[10];
  const float* WE2 = (const float*)d_in[11];
  const float* gv1 = (const float*)d_in[12];
  const float* bv1 = (const float*)d_in[13];
  const float* ge1 = (const float*)d_in[14];
  const float* be1 = (const float*)d_in[15];
  const float* gv2 = (const float*)d_in[16];
  const float* bv2 = (const float*)d_in[17];
  const float* ge2 = (const float*)d_in[18];
  const float* be2 = (const float*)d_in[19];

  char* ws = (char*)d_ws;
  u16*   wbf  = (u16*)(ws + 0);           // 10 x 512x512 bf16 = 5,242,880 B
  float* V4   = (float*)(ws + 5242880);   // [1728, 2048] fp32 = 14,155,776 B
  u16*   msg  = (u16*)(ws + 19398656);    // [46656, 512] bf16 = 47,775,744 B
  float* xnew = (float*)(ws + 67174400);  // [1728, 512] fp32
  float* x1   = (float*)(ws + 70713344);  // [1728, 512] fp32
  float* st   = (float*)(ws + 74252288);  // stats block
  float* es1 = st + 0;    float* eq1 = st + 768;
  float* es2 = st + 1536; float* eq2 = st + 2304;
  float* vs1 = st + 3072; float* vq1 = st + 3104;
  float* vs2 = st + 3136; float* vq2 = st + 3168;
  float2* eab1 = (float2*)(st + 3200);
  float2* eab2 = (float2*)(st + 4672);

  float* xout = (float*)d_out;                 // [64,27,512]
  float* eo   = (float*)d_out + 884736;        // [64,729,512] (layer1 edge lives here, updated in place by layer2)

  hipMemsetAsync(st, 0, 3200 * sizeof(float), stream);
  convw_k<<<dim3(10240), dim3(256), 0, stream>>>(WA1, WB1, WU1, WV1, WE1, WA2, WB2, WU2, WV2, WE2, wbf);

  // ---- layer 1 ----
  gemm_k<1><<<dim3(8, 27), dim3(256), 0, stream>>>(x, wbf, V4, 2048, nullptr, nullptr, nullptr, nullptr);
  gemm_k<2><<<dim3(2, 729), dim3(256), 0, stream>>>(edge, wbf + 4 * 262144, nullptr, 0, msg, V4, es1, eq1);
  eab_fin_k<<<dim3(3), dim3(256), 0, stream>>>(es1, eq1, ge1, be1, eab1, 729);
  edge_attn_k<<<dim3(1728), dim3(512), 0, stream>>>(msg, edge, eo, eab1, V4, xnew, vs1, vq1);
  vert_bn_k<<<dim3(3456), dim3(256), 0, stream>>>(xnew, x, vs1, vq1, gv1, bv1, x1);

  // ---- layer 2 ----
  gemm_k<1><<<dim3(8, 27), dim3(256), 0, stream>>>(x1, wbf + 5 * 262144, V4, 2048, nullptr, nullptr, nullptr, nullptr);
  gemm_k<2><<<dim3(2, 729), dim3(256), 0, stream>>>(eo, wbf + 9 * 262144, nullptr, 0, msg, V4, es2, eq2);
  eab_fin_k<<<dim3(3), dim3(256), 0, stream>>>(es2, eq2, ge2, be2, eab2, 729);
  edge_attn_k<<<dim3(1728), dim3(512), 0, stream>>>(msg, eo, eo, eab2, V4, xnew, vs2, vq2);
  vert_bn_k<<<dim3(3456), dim3(256), 0, stream>>>(xnew, x1, vs2, vq2, gv2, bv2, xout);
}

// Round 2
// 480.242 us; speedup vs baseline: 1.0834x; 1.0834x over previous
//
#include <hip/hip_runtime.h>

typedef unsigned short u16;
typedef unsigned int u32;
typedef __bf16 bf16x8 __attribute__((ext_vector_type(8)));
typedef float f32x4 __attribute__((ext_vector_type(4)));

#define DI __device__ __forceinline__

DI u16 f2bf(float f) {
  union { float f; u32 u; } v; v.f = f;
  return (u16)((v.u + 0x7fffu + ((v.u >> 16) & 1u)) >> 16);
}
DI float bf2f(u16 h) {
  union { u32 u; float f; } v; v.u = ((u32)h) << 16;
  return v.f;
}

// async 16B global->LDS (dest = wave-uniform base + lane*16)
DI void gload_lds16(const void* g, void* l) {
  __builtin_amdgcn_global_load_lds((const __attribute__((address_space(1))) u32*)g,
                                   (__attribute__((address_space(3))) u32*)l, 16, 0, 0);
}

constexpr float INV_M = 1.0f / 32768.0f;  // 1/(B*C)

// ---------------- weight convert: 10 x [512,512] fp32 -> bf16, float4 vectorized ----------------
__global__ void convw_k(const float* wa1, const float* wb1, const float* wu1, const float* wv1, const float* we1,
                        const float* wa2, const float* wb2, const float* wu2, const float* wv2, const float* we2,
                        u16* dst) {
  int idx = blockIdx.x * 256 + threadIdx.x;   // group of 4 floats
  int m = idx >> 16;                          // 65536 groups per matrix
  int i = (idx & 0xffff) << 2;
  const float* s;
  switch (m) {
    case 0: s = wa1; break; case 1: s = wb1; break; case 2: s = wu1; break;
    case 3: s = wv1; break; case 4: s = we1; break; case 5: s = wa2; break;
    case 6: s = wb2; break; case 7: s = wu2; break; case 8: s = wv2; break;
    default: s = we2; break;
  }
  float4 v = *(const float4*)(s + i);
  ushort4 o;
  o.x = f2bf(v.x); o.y = f2bf(v.y); o.z = f2bf(v.z); o.w = f2bf(v.w);
  *(ushort4*)(dst + ((size_t)m << 18) + i) = o;
}

// ---------------- GEMM: out[m,n] = sum_k A[m,k] * W[n,k] ----------------
// BM=64, BN=128, BK=64, 256 threads (4 waves 2x2), wave tile 32x64.
// LDS 24KB (XOR-swizzled, no pad) -> high occupancy. W staged via global_load_lds.
// ABF: A is bf16 (async stage) vs fp32 (VGPR convert stage).
// EPI==1: fp32 store to outf. EPI==2: msg=acc+Vix+Vjx -> bf16 + fused edge stats.
template<int EPI, int ABF>
__global__ __launch_bounds__(256, 5) void gemm_k(
    const void* __restrict__ A_, const u16* __restrict__ W,
    float* __restrict__ outf, int ldout,
    u16* __restrict__ msg, const float* __restrict__ V4,
    float* __restrict__ esum, float* __restrict__ esq) {
  __shared__ __align__(16) u16 lA[64 * 64];    // [row][g^(row&7) swizzled granules]
  __shared__ __align__(16) u16 lW[128 * 64];
  const int tid = threadIdx.x;
  const int lane = tid & 63, wid = tid >> 6;
  const int wm = wid >> 1, wn = wid & 1;
  const int q = lane >> 4, l15 = lane & 15;
  const int rb = blockIdx.y, cb = blockIdx.x;
  const int lrow8 = lane >> 3, lg = lane & 7;

  f32x4 acc[2][4];
#pragma unroll
  for (int a = 0; a < 2; a++)
#pragma unroll
    for (int b = 0; b < 4; b++) acc[a][b] = (f32x4){0.f, 0.f, 0.f, 0.f};

  for (int k0 = 0; k0 < 512; k0 += 64) {
    __syncthreads();
    // ---- stage A tile (64 rows x 64 k) ----
    if (ABF) {
#pragma unroll
      for (int it = 0; it < 2; it++) {
        int ch = wid * 2 + it;
        int row = ch * 8 + lrow8;
        const u16* src = (const u16*)A_ + (((size_t)(rb * 64 + row)) << 9) + k0 + ((lg ^ (row & 7)) << 3);
        gload_lds16(src, lA + ch * 512);
      }
    } else {
#pragma unroll
      for (int s = tid; s < 512; s += 256) {
        int row = s >> 3, g = s & 7;
        const float* src = (const float*)A_ + (((size_t)(rb * 64 + row)) << 9) + k0 + g * 8;
        float4 s0 = *(const float4*)src;
        float4 s1 = *(const float4*)(src + 4);
        uint4 p;
        p.x = f2bf(s0.x) | ((u32)f2bf(s0.y) << 16);
        p.y = f2bf(s0.z) | ((u32)f2bf(s0.w) << 16);
        p.z = f2bf(s1.x) | ((u32)f2bf(s1.y) << 16);
        p.w = f2bf(s1.z) | ((u32)f2bf(s1.w) << 16);
        *(uint4*)(lA + row * 64 + ((g ^ (row & 7)) << 3)) = p;
      }
    }
    // ---- stage W tile (128 rows x 64 k), async ----
#pragma unroll
    for (int it = 0; it < 4; it++) {
      int ch = wid * 4 + it;
      int row = ch * 8 + lrow8;
      const u16* src = W + (((size_t)(cb * 128 + row)) << 9) + k0 + ((lg ^ (row & 7)) << 3);
      gload_lds16(src, lW + ch * 512);
    }
    __syncthreads();
    // ---- compute ----
#pragma unroll
    for (int ks = 0; ks < 2; ks++) {
      const int gk = ks * 4 + q;
      bf16x8 af[2], wf[4];
#pragma unroll
      for (int mt = 0; mt < 2; mt++) {
        int r = wm * 32 + mt * 16 + l15;
        af[mt] = *(const bf16x8*)(lA + r * 64 + ((gk ^ (r & 7)) << 3));
      }
#pragma unroll
      for (int nt = 0; nt < 4; nt++) {
        int r = wn * 64 + nt * 16 + l15;
        wf[nt] = *(const bf16x8*)(lW + r * 64 + ((gk ^ (r & 7)) << 3));
      }
#pragma unroll
      for (int mt = 0; mt < 2; mt++)
#pragma unroll
        for (int nt = 0; nt < 4; nt++)
          acc[mt][nt] = __builtin_amdgcn_mfma_f32_16x16x32_bf16(af[mt], wf[nt], acc[mt][nt], 0, 0, 0);
    }
  }

  if (EPI == 1) {
#pragma unroll
    for (int mt = 0; mt < 2; mt++) {
      int grow0 = rb * 64 + wm * 32 + mt * 16 + q * 4;
#pragma unroll
      for (int nt = 0; nt < 4; nt++) {
        int gcol = cb * 128 + wn * 64 + nt * 16 + l15;
#pragma unroll
        for (int r = 0; r < 4; r++)
          outf[(size_t)(grow0 + r) * ldout + gcol] = acc[mt][nt][r];
      }
    }
  } else {
    // msg = acc + Vix[b,i,:] + Vjx[b,j,:]; row = b*729 + i*27 + j
    float ms[2][4], m2[2][4];
#pragma unroll
    for (int mt = 0; mt < 2; mt++) {
#pragma unroll
      for (int r = 0; r < 4; r++) {
        int grow = rb * 64 + wm * 32 + mt * 16 + q * 4 + r;
        int b = grow / 729;
        int e = grow - b * 729;
        int i = e / 27;
        int j = e - i * 27;
        const float* vix = V4 + (((size_t)(b * 27 + i)) << 11);
        const float* vjx = V4 + (((size_t)(b * 27 + j)) << 11) + 512;
        u16* mrow = msg + (((size_t)grow) << 9);
        float s1 = 0.f, s2 = 0.f;
#pragma unroll
        for (int nt = 0; nt < 4; nt++) {
          int c = cb * 128 + wn * 64 + nt * 16 + l15;
          float m = acc[mt][nt][r] + vix[c] + vjx[c];
          mrow[c] = f2bf(m);
          s1 += m;
          s2 += m * m;
        }
        ms[mt][r] = s1;
        m2[mt][r] = s2;
      }
    }
#pragma unroll
    for (int msk = 1; msk < 16; msk <<= 1) {
#pragma unroll
      for (int mt = 0; mt < 2; mt++)
#pragma unroll
        for (int r = 0; r < 4; r++) {
          ms[mt][r] += __shfl_xor(ms[mt][r], msk);
          m2[mt][r] += __shfl_xor(m2[mt][r], msk);
        }
    }
    __syncthreads();
    float* sm = (float*)lA;  // 256 floats scratch
    if (l15 == 0) {
#pragma unroll
      for (int mt = 0; mt < 2; mt++)
#pragma unroll
        for (int r = 0; r < 4; r++) {
          int rib = wm * 32 + mt * 16 + q * 4 + r;
          sm[wn * 64 + rib] = ms[mt][r];
          sm[128 + wn * 64 + rib] = m2[mt][r];
        }
    }
    __syncthreads();
    if (tid < 64) {
      int grow = rb * 64 + tid;
      int e = grow % 729;
      atomicAdd(&esum[e], sm[tid] + sm[64 + tid]);
      atomicAdd(&esq[e], sm[128 + tid] + sm[192 + tid]);
    }
  }
}

// ---------------- fused: eab; eout = ein + relu(bn(msg)); sigmoid+softmax_j; agg; xnew; vstats ----------------
template<int INBF, int OUTBF>
__global__ __launch_bounds__(512) void edge_attn_k(
    const u16* msg, const void* ein_, void* eout_,
    const float* __restrict__ esum, const float* __restrict__ esq,
    const float* __restrict__ ge, const float* __restrict__ be,
    const float* __restrict__ V4,
    float* __restrict__ xnew, float* __restrict__ vsum, float* __restrict__ vsq) {
  const int bi = blockIdx.x;          // b*27 + i
  const int b = bi / 27, i = bi - b * 27;
  const int c = threadIdx.x;
  __shared__ float2 sab[27];
  if (c < 27) {
    int e = i * 27 + c;
    float mean = esum[e] * INV_M;
    float var = esq[e] * INV_M - mean * mean;
    float a = ge[e] * rsqrtf(var + 1e-5f);
    sab[c] = make_float2(a, be[e] - mean * a);
  }
  __syncthreads();
  const size_t ebase = (((size_t)(b * 729 + i * 27)) << 9) + c;
  const u16* einb = (const u16*)ein_;
  const float* einf = (const float*)ein_;
  u16* eoutb = (u16*)eout_;
  float* eoutf = (float*)eout_;
  float texp[27];
  float ssum = 0.f;
#pragma unroll
  for (int j = 0; j < 27; j++) {
    size_t idx = ebase + (((size_t)j) << 9);
    float2 ab = sab[j];
    float bn = fmaf(ab.x, bf2f(msg[idx]), ab.y);
    float ei = INBF ? bf2f(einb[idx]) : einf[idx];
    float eo = ei + fmaxf(bn, 0.f);
    if (OUTBF) eoutb[idx] = f2bf(eo); else eoutf[idx] = eo;
    float s = 1.f / (1.f + __expf(-eo));
    float t = __expf(s);
    ssum += t;
    texp[j] = t;
  }
  float accv = 0.f;
#pragma unroll
  for (int j = 0; j < 27; j++)
    accv = fmaf(texp[j], V4[(((size_t)(b * 27 + j)) << 11) + 1536 + c], accv);  // Ujx
  float xn = V4[(((size_t)(b * 27 + i)) << 11) + 1024 + c] + accv / (ssum * 27.f);  // Uix + agg/N
  xnew[(((size_t)bi) << 9) + c] = xn;
  float v = xn, v2 = xn * xn;
#pragma unroll
  for (int m = 32; m >= 1; m >>= 1) {
    v += __shfl_xor(v, m);
    v2 += __shfl_xor(v2, m);
  }
  __shared__ float red[16];
  int w = threadIdx.x >> 6, ln = threadIdx.x & 63;
  if (ln == 0) { red[w] = v; red[8 + w] = v2; }
  __syncthreads();
  if (threadIdx.x == 0) {
    float s1 = 0.f, s2 = 0.f;
#pragma unroll
    for (int k = 0; k < 8; k++) { s1 += red[k]; s2 += red[8 + k]; }
    atomicAdd(&vsum[i], s1);
    atomicAdd(&vsq[i], s2);
  }
}

// ---------------- x_out = relu(res + bn_v(xnew)) ----------------
__global__ void vert_bn_k(const float* __restrict__ xnew, const float* __restrict__ res,
                          const float* __restrict__ vsum, const float* __restrict__ vsq,
                          const float* __restrict__ g, const float* __restrict__ bt,
                          float* __restrict__ out) {
  int idx = blockIdx.x * 256 + threadIdx.x;
  int i = (idx >> 9) % 27;
  float mean = vsum[i] * INV_M;
  float var = vsq[i] * INV_M - mean * mean;
  float rs = rsqrtf(var + 1e-5f);
  float a = g[i] * rs;
  float bb = bt[i] - mean * a;
  out[idx] = fmaxf(res[idx] + fmaf(a, xnew[idx], bb), 0.f);
}

extern "C" void kernel_launch(void* const* d_in, const int* in_sizes, int n_in,
                              void* d_out, int out_size, void* d_ws, size_t ws_size,
                              hipStream_t stream) {
  const float* x    = (const float*)d_in[0];
  const float* edge = (const float*)d_in[1];
  const float* WU1 = (const float*)d_in[2];
  const float* WV1 = (const float*)d_in[3];
  const float* WA1 = (const float*)d_in[4];
  const float* WB1 = (const float*)d_in[5];
  const float* WE1 = (const float*)d_in[6];
  const float* WU2 = (const float*)d_in[7];
  const float* WV2 = (const float*)d_in[8];
  const float* WA2 = (const float*)d_in[9];
  const float* WB2 = (const float*)d_in[10];
  const float* WE2 = (const float*)d_in[11];
  const float* gv1 = (const float*)d_in[12];
  const float* bv1 = (const float*)d_in[13];
  const float* ge1 = (const float*)d_in[14];
  const float* be1 = (const float*)d_in[15];
  const float* gv2 = (const float*)d_in[16];
  const float* bv2 = (const float*)d_in[17];
  const float* ge2 = (const float*)d_in[18];
  const float* be2 = (const float*)d_in[19];

  char* ws = (char*)d_ws;
  u16*   wbf  = (u16*)(ws + 0);            //  5,242,880 B (10 x 512x512 bf16)
  float* V4   = (float*)(ws + 5242880);    // 14,155,776 B [1728,2048]
  u16*   M1   = (u16*)(ws + 19398656);     // 47,775,744 B [46656,512] bf16
  u16*   M2   = (u16*)(ws + 67174400);     // 47,775,744 B
  float* xnew = (float*)(ws + 114950144);  //  3,538,944 B
  float* x1   = (float*)(ws + 118489088);  //  3,538,944 B
  float* st   = (float*)(ws + 122028032);  // stats
  float* es1 = st;         float* eq1 = st + 729;
  float* es2 = st + 1458;  float* eq2 = st + 2187;
  float* vs1 = st + 2916;  float* vq1 = st + 2943;
  float* vs2 = st + 2970;  float* vq2 = st + 2997;

  float* xout = (float*)d_out;             // [64,27,512]
  float* eo   = (float*)d_out + 884736;    // [64,729,512] final edge (fp32)

  hipMemsetAsync(st, 0, 3024 * sizeof(float), stream);
  convw_k<<<dim3(2560), dim3(256), 0, stream>>>(WA1, WB1, WU1, WV1, WE1, WA2, WB2, WU2, WV2, WE2, wbf);

  // ---- layer 1 ----
  gemm_k<1, 0><<<dim3(16, 27), dim3(256), 0, stream>>>(x, wbf, V4, 2048, nullptr, nullptr, nullptr, nullptr);
  gemm_k<2, 0><<<dim3(4, 729), dim3(256), 0, stream>>>(edge, wbf + 4 * 262144, nullptr, 0, M1, V4, es1, eq1);
  // eout (intermediate edge) -> bf16, in place over M1
  edge_attn_k<0, 1><<<dim3(1728), dim3(512), 0, stream>>>(M1, edge, M1, es1, eq1, ge1, be1, V4, xnew, vs1, vq1);
  vert_bn_k<<<dim3(3456), dim3(256), 0, stream>>>(xnew, x, vs1, vq1, gv1, bv1, x1);

  // ---- layer 2 ----
  gemm_k<1, 0><<<dim3(16, 27), dim3(256), 0, stream>>>(x1, wbf + 5 * 262144, V4, 2048, nullptr, nullptr, nullptr, nullptr);
  gemm_k<2, 1><<<dim3(4, 729), dim3(256), 0, stream>>>(M1, wbf + 9 * 262144, nullptr, 0, M2, V4, es2, eq2);
  edge_attn_k<1, 0><<<dim3(1728), dim3(512), 0, stream>>>(M2, M1, eo, es2, eq2, ge2, be2, V4, xnew, vs2, vq2);
  vert_bn_k<<<dim3(3456), dim3(256), 0, stream>>>(xnew, x1, vs2, vq2, gv2, bv2, xout);
}

// Round 3
// 442.043 us; speedup vs baseline: 1.1771x; 1.0864x over previous
//
#include <hip/hip_runtime.h>

typedef unsigned short u16;
typedef unsigned int u32;
typedef __bf16 bf16x8 __attribute__((ext_vector_type(8)));
typedef float f32x4 __attribute__((ext_vector_type(4)));

#define DI __device__ __forceinline__

DI u16 f2bf(float f) {
  union { float f; u32 u; } v; v.f = f;
  return (u16)((v.u + 0x7fffu + ((v.u >> 16) & 1u)) >> 16);
}
DI float bf2f(u16 h) {
  union { u32 u; float f; } v; v.u = ((u32)h) << 16;
  return v.f;
}

// async 16B global->LDS (dest = wave-uniform base + lane*16)
DI void gload_lds16(const void* g, void* l) {
  __builtin_amdgcn_global_load_lds((const __attribute__((address_space(1))) u32*)g,
                                   (__attribute__((address_space(3))) u32*)l, 16, 0, 0);
}

constexpr float INV_M = 1.0f / 32768.0f;  // 1/(B*C)

// ---------------- weight convert: 10 x [512,512] fp32 -> bf16 ----------------
__global__ void convw_k(const float* wa1, const float* wb1, const float* wu1, const float* wv1, const float* we1,
                        const float* wa2, const float* wb2, const float* wu2, const float* wv2, const float* we2,
                        u16* dst) {
  int idx = blockIdx.x * 256 + threadIdx.x;   // group of 4 floats
  int m = idx >> 16;
  int i = (idx & 0xffff) << 2;
  const float* s;
  switch (m) {
    case 0: s = wa1; break; case 1: s = wb1; break; case 2: s = wu1; break;
    case 3: s = wv1; break; case 4: s = we1; break; case 5: s = wa2; break;
    case 6: s = wb2; break; case 7: s = wu2; break; case 8: s = wv2; break;
    default: s = we2; break;
  }
  float4 v = *(const float4*)(s + i);
  ushort4 o;
  o.x = f2bf(v.x); o.y = f2bf(v.y); o.z = f2bf(v.z); o.w = f2bf(v.w);
  *(ushort4*)(dst + ((size_t)m << 18) + i) = o;
}

// ---------------- GEMM: out[m,n] = sum_k A[m,k] * W[n,k] ----------------
// BM=64, BN=32*NT, BK=64, 256 threads (4 waves 2x2), wave tile 32 x 16*NT.
// XOR-swizzled LDS, W (and bf16 A) staged via global_load_lds.
// SWZ: 1-D grid, XCD-aware remap so all cb-blocks of one rb share an XCD (L2 A-tile reuse).
// EPI==1: fp32 store. EPI==2: msg=acc+Vix+Vjx -> bf16 + fused edge BN stats.
template<int EPI, int ABF, int SWZ, int NT>
__global__ __launch_bounds__(256, 5) void gemm_k(
    const void* __restrict__ A_, const u16* __restrict__ W,
    float* __restrict__ outf, int ldout,
    u16* __restrict__ msg, const float* __restrict__ V4,
    float* __restrict__ esum, float* __restrict__ esq) {
  __shared__ __align__(16) u16 lA[64 * 64];
  __shared__ __align__(16) u16 lW[32 * NT * 64];
  const int tid = threadIdx.x;
  const int lane = tid & 63, wid = tid >> 6;
  const int wm = wid >> 1, wn = wid & 1;
  const int q = lane >> 4, l15 = lane & 15;
  const int lrow8 = lane >> 3, lg = lane & 7;

  int rb, cb;
  if (SWZ) {
    // l%8 = XCD slot; group 4 cbs of one rb at ids {l, l+8, l+16, l+24} -> same XCD
    int l = blockIdx.x;
    int xcd = l & 7, t = l >> 3;
    cb = t & 3;
    rb = ((t >> 2) << 3) | xcd;
    if (rb >= 729) return;
  } else {
    rb = blockIdx.y; cb = blockIdx.x;
  }

  f32x4 acc[2][NT];
#pragma unroll
  for (int a = 0; a < 2; a++)
#pragma unroll
    for (int b = 0; b < NT; b++) acc[a][b] = (f32x4){0.f, 0.f, 0.f, 0.f};

  for (int k0 = 0; k0 < 512; k0 += 64) {
    __syncthreads();
    // ---- stage A tile (64 rows x 64 k) ----
    if (ABF) {
#pragma unroll
      for (int it = 0; it < 2; it++) {
        int ch = wid * 2 + it;
        int row = ch * 8 + lrow8;
        const u16* src = (const u16*)A_ + (((size_t)(rb * 64 + row)) << 9) + k0 + ((lg ^ (row & 7)) << 3);
        gload_lds16(src, lA + ch * 512);
      }
    } else {
#pragma unroll
      for (int s = tid; s < 512; s += 256) {
        int row = s >> 3, g = s & 7;
        const float* src = (const float*)A_ + (((size_t)(rb * 64 + row)) << 9) + k0 + g * 8;
        float4 s0 = *(const float4*)src;
        float4 s1 = *(const float4*)(src + 4);
        uint4 p;
        p.x = f2bf(s0.x) | ((u32)f2bf(s0.y) << 16);
        p.y = f2bf(s0.z) | ((u32)f2bf(s0.w) << 16);
        p.z = f2bf(s1.x) | ((u32)f2bf(s1.y) << 16);
        p.w = f2bf(s1.z) | ((u32)f2bf(s1.w) << 16);
        *(uint4*)(lA + row * 64 + ((g ^ (row & 7)) << 3)) = p;
      }
    }
    // ---- stage W tile (32*NT rows x 64 k), async ----
#pragma unroll
    for (int it = 0; it < NT; it++) {
      int ch = wid * NT + it;
      int row = ch * 8 + lrow8;
      const u16* src = W + (((size_t)(cb * 32 * NT + row)) << 9) + k0 + ((lg ^ (row & 7)) << 3);
      gload_lds16(src, lW + ch * 512);
    }
    __syncthreads();
    // ---- compute ----
#pragma unroll
    for (int ks = 0; ks < 2; ks++) {
      const int gk = ks * 4 + q;
      bf16x8 af[2], wf[NT];
#pragma unroll
      for (int mt = 0; mt < 2; mt++) {
        int r = wm * 32 + mt * 16 + l15;
        af[mt] = *(const bf16x8*)(lA + r * 64 + ((gk ^ (r & 7)) << 3));
      }
#pragma unroll
      for (int nt = 0; nt < NT; nt++) {
        int r = wn * 16 * NT + nt * 16 + l15;
        wf[nt] = *(const bf16x8*)(lW + r * 64 + ((gk ^ (r & 7)) << 3));
      }
#pragma unroll
      for (int mt = 0; mt < 2; mt++)
#pragma unroll
        for (int nt = 0; nt < NT; nt++)
          acc[mt][nt] = __builtin_amdgcn_mfma_f32_16x16x32_bf16(af[mt], wf[nt], acc[mt][nt], 0, 0, 0);
    }
  }

  if (EPI == 1) {
#pragma unroll
    for (int mt = 0; mt < 2; mt++) {
      int grow0 = rb * 64 + wm * 32 + mt * 16 + q * 4;
#pragma unroll
      for (int nt = 0; nt < NT; nt++) {
        int gcol = cb * 32 * NT + wn * 16 * NT + nt * 16 + l15;
#pragma unroll
        for (int r = 0; r < 4; r++)
          outf[(size_t)(grow0 + r) * ldout + gcol] = acc[mt][nt][r];
      }
    }
  } else {
    // msg = acc + Vix[b,i,:] + Vjx[b,j,:]; row = b*729 + i*27 + j
    float ms[2][4], m2[2][4];
#pragma unroll
    for (int mt = 0; mt < 2; mt++) {
#pragma unroll
      for (int r = 0; r < 4; r++) {
        int grow = rb * 64 + wm * 32 + mt * 16 + q * 4 + r;
        int b = grow / 729;
        int e = grow - b * 729;
        int i = e / 27;
        int j = e - i * 27;
        const float* vix = V4 + (((size_t)(b * 27 + i)) << 11);
        const float* vjx = V4 + (((size_t)(b * 27 + j)) << 11) + 512;
        u16* mrow = msg + (((size_t)grow) << 9);
        float s1 = 0.f, s2 = 0.f;
#pragma unroll
        for (int nt = 0; nt < NT; nt++) {
          int c = cb * 32 * NT + wn * 16 * NT + nt * 16 + l15;
          float m = acc[mt][nt][r] + vix[c] + vjx[c];
          mrow[c] = f2bf(m);
          s1 += m;
          s2 += m * m;
        }
        ms[mt][r] = s1;
        m2[mt][r] = s2;
      }
    }
#pragma unroll
    for (int msk = 1; msk < 16; msk <<= 1) {
#pragma unroll
      for (int mt = 0; mt < 2; mt++)
#pragma unroll
        for (int r = 0; r < 4; r++) {
          ms[mt][r] += __shfl_xor(ms[mt][r], msk);
          m2[mt][r] += __shfl_xor(m2[mt][r], msk);
        }
    }
    __syncthreads();
    float* sm = (float*)lA;
    if (l15 == 0) {
#pragma unroll
      for (int mt = 0; mt < 2; mt++)
#pragma unroll
        for (int r = 0; r < 4; r++) {
          int rib = wm * 32 + mt * 16 + q * 4 + r;
          sm[wn * 64 + rib] = ms[mt][r];
          sm[128 + wn * 64 + rib] = m2[mt][r];
        }
    }
    __syncthreads();
    if (tid < 64) {
      int grow = rb * 64 + tid;
      int e = grow % 729;
      atomicAdd(&esum[e], sm[tid] + sm[64 + tid]);
      atomicAdd(&esq[e], sm[128 + tid] + sm[192 + tid]);
    }
  }
}

// ---------------- fused: eab; eout = ein + relu(bn(msg)); sigmoid+softmax_j; agg; xnew; vstats ----------------
// 256 threads, 2 channels/thread, packed loads.
template<int INBF, int OUTBF>
__global__ __launch_bounds__(256) void edge_attn_k(
    const u16* __restrict__ msg, const void* __restrict__ ein_, void* __restrict__ eout_,
    const float* __restrict__ esum, const float* __restrict__ esq,
    const float* __restrict__ ge, const float* __restrict__ be,
    const float* __restrict__ V4,
    float* __restrict__ xnew, float* __restrict__ vsum, float* __restrict__ vsq) {
  const int bi = blockIdx.x;          // b*27 + i
  const int b = bi / 27, i = bi - b * 27;
  const int t = threadIdx.x;          // channels 2t, 2t+1
  __shared__ float2 sab[27];
  if (t < 27) {
    int e = i * 27 + t;
    float mean = esum[e] * INV_M;
    float var = esq[e] * INV_M - mean * mean;
    float a = ge[e] * rsqrtf(var + 1e-5f);
    sab[t] = make_float2(a, be[e] - mean * a);
  }
  __syncthreads();
  const size_t ebase = (((size_t)(b * 729 + i * 27)) << 9) + 2 * t;
  const u16* einb = (const u16*)ein_;
  const float* einf = (const float*)ein_;
  u16* eoutb = (u16*)eout_;
  float* eoutf = (float*)eout_;
  float t0[27], t1[27];
  float ss0 = 0.f, ss1 = 0.f;
#pragma unroll
  for (int j = 0; j < 27; j++) {
    size_t idx = ebase + (((size_t)j) << 9);
    float2 ab = sab[j];
    u32 mp = *(const u32*)(msg + idx);
    float2 ei;
    if (INBF) {
      u32 ep = *(const u32*)(einb + idx);
      ei = make_float2(bf2f((u16)ep), bf2f((u16)(ep >> 16)));
    } else {
      ei = *(const float2*)(einf + idx);
    }
    float e0 = ei.x + fmaxf(fmaf(ab.x, bf2f((u16)mp), ab.y), 0.f);
    float e1 = ei.y + fmaxf(fmaf(ab.x, bf2f((u16)(mp >> 16)), ab.y), 0.f);
    if (OUTBF) {
      *(u32*)(eoutb + idx) = (u32)f2bf(e0) | ((u32)f2bf(e1) << 16);
    } else {
      *(float2*)(eoutf + idx) = make_float2(e0, e1);
    }
    float x0 = __expf(1.f / (1.f + __expf(-e0)));
    float x1 = __expf(1.f / (1.f + __expf(-e1)));
    ss0 += x0; ss1 += x1;
    t0[j] = x0; t1[j] = x1;
  }
  float a0 = 0.f, a1 = 0.f;
#pragma unroll
  for (int j = 0; j < 27; j++) {
    float2 uj = *(const float2*)(V4 + (((size_t)(b * 27 + j)) << 11) + 1536 + 2 * t);  // Ujx
    a0 = fmaf(t0[j], uj.x, a0);
    a1 = fmaf(t1[j], uj.y, a1);
  }
  float2 ui = *(const float2*)(V4 + (((size_t)(b * 27 + i)) << 11) + 1024 + 2 * t);    // Uix
  float xn0 = ui.x + a0 / (ss0 * 27.f);
  float xn1 = ui.y + a1 / (ss1 * 27.f);
  *(float2*)(xnew + (((size_t)bi) << 9) + 2 * t) = make_float2(xn0, xn1);
  float v = xn0 + xn1, v2 = xn0 * xn0 + xn1 * xn1;
#pragma unroll
  for (int m = 32; m >= 1; m >>= 1) {
    v += __shfl_xor(v, m);
    v2 += __shfl_xor(v2, m);
  }
  __shared__ float red[8];
  int w = t >> 6, ln = t & 63;
  if (ln == 0) { red[w] = v; red[4 + w] = v2; }
  __syncthreads();
  if (t == 0) {
    float s1 = 0.f, s2 = 0.f;
#pragma unroll
    for (int k = 0; k < 4; k++) { s1 += red[k]; s2 += red[4 + k]; }
    atomicAdd(&vsum[i], s1);
    atomicAdd(&vsq[i], s2);
  }
}

// ---------------- x_out = relu(res + bn_v(xnew)), float4 ----------------
__global__ void vert_bn_k(const float4* __restrict__ xnew, const float4* __restrict__ res,
                          const float* __restrict__ vsum, const float* __restrict__ vsq,
                          const float* __restrict__ g, const float* __restrict__ bt,
                          float4* __restrict__ out) {
  int idx = blockIdx.x * 256 + threadIdx.x;   // float4 index, 221184 total
  int i = (idx >> 7) % 27;
  float mean = vsum[i] * INV_M;
  float var = vsq[i] * INV_M - mean * mean;
  float a = g[i] * rsqrtf(var + 1e-5f);
  float bb = bt[i] - mean * a;
  float4 xv = xnew[idx];
  float4 rv = res[idx];
  float4 o;
  o.x = fmaxf(rv.x + fmaf(a, xv.x, bb), 0.f);
  o.y = fmaxf(rv.y + fmaf(a, xv.y, bb), 0.f);
  o.z = fmaxf(rv.z + fmaf(a, xv.z, bb), 0.f);
  o.w = fmaxf(rv.w + fmaf(a, xv.w, bb), 0.f);
  out[idx] = o;
}

extern "C" void kernel_launch(void* const* d_in, const int* in_sizes, int n_in,
                              void* d_out, int out_size, void* d_ws, size_t ws_size,
                              hipStream_t stream) {
  const float* x    = (const float*)d_in[0];
  const float* edge = (const float*)d_in[1];
  const float* WU1 = (const float*)d_in[2];
  const float* WV1 = (const float*)d_in[3];
  const float* WA1 = (const float*)d_in[4];
  const float* WB1 = (const float*)d_in[5];
  const float* WE1 = (const float*)d_in[6];
  const float* WU2 = (const float*)d_in[7];
  const float* WV2 = (const float*)d_in[8];
  const float* WA2 = (const float*)d_in[9];
  const float* WB2 = (const float*)d_in[10];
  const float* WE2 = (const float*)d_in[11];
  const float* gv1 = (const float*)d_in[12];
  const float* bv1 = (const float*)d_in[13];
  const float* ge1 = (const float*)d_in[14];
  const float* be1 = (const float*)d_in[15];
  const float* gv2 = (const float*)d_in[16];
  const float* bv2 = (const float*)d_in[17];
  const float* ge2 = (const float*)d_in[18];
  const float* be2 = (const float*)d_in[19];

  char* ws = (char*)d_ws;
  u16*   wbf  = (u16*)(ws + 0);            //  5,242,880 B (10 x 512x512 bf16)
  float* V4   = (float*)(ws + 5242880);    // 14,155,776 B [1728,2048]
  u16*   M1   = (u16*)(ws + 19398656);     // 47,775,744 B [46656,512] bf16
  u16*   M2   = (u16*)(ws + 67174400);     // 47,775,744 B
  float* xnew = (float*)(ws + 114950144);  //  3,538,944 B
  float* x1   = (float*)(ws + 118489088);  //  3,538,944 B
  float* st   = (float*)(ws + 122028032);  // stats
  float* es1 = st;         float* eq1 = st + 729;
  float* es2 = st + 1458;  float* eq2 = st + 2187;
  float* vs1 = st + 2916;  float* vq1 = st + 2943;
  float* vs2 = st + 2970;  float* vq2 = st + 2997;

  float* xout = (float*)d_out;             // [64,27,512]
  float* eo   = (float*)d_out + 884736;    // [64,729,512] final edge (fp32)

  hipMemsetAsync(st, 0, 3024 * sizeof(float), stream);
  convw_k<<<dim3(2560), dim3(256), 0, stream>>>(WA1, WB1, WU1, WV1, WE1, WA2, WB2, WU2, WV2, WE2, wbf);

  // ---- layer 1 ----
  gemm_k<1, 0, 0, 2><<<dim3(32, 27), dim3(256), 0, stream>>>(x, wbf, V4, 2048, nullptr, nullptr, nullptr, nullptr);
  gemm_k<2, 0, 1, 4><<<dim3(2944), dim3(256), 0, stream>>>(edge, wbf + 4 * 262144, nullptr, 0, M1, V4, es1, eq1);
  edge_attn_k<0, 1><<<dim3(1728), dim3(256), 0, stream>>>(M1, edge, M1, es1, eq1, ge1, be1, V4, xnew, vs1, vq1);
  vert_bn_k<<<dim3(864), dim3(256), 0, stream>>>((const float4*)xnew, (const float4*)x, vs1, vq1, gv1, bv1, (float4*)x1);

  // ---- layer 2 ----
  gemm_k<1, 0, 0, 2><<<dim3(32, 27), dim3(256), 0, stream>>>(x1, wbf + 5 * 262144, V4, 2048, nullptr, nullptr, nullptr, nullptr);
  gemm_k<2, 1, 1, 4><<<dim3(2944), dim3(256), 0, stream>>>(M1, wbf + 9 * 262144, nullptr, 0, M2, V4, es2, eq2);
  edge_attn_k<1, 0><<<dim3(1728), dim3(256), 0, stream>>>(M2, M1, eo, es2, eq2, ge2, be2, V4, xnew, vs2, vq2);
  vert_bn_k<<<dim3(864), dim3(256), 0, stream>>>((const float4*)xnew, (const float4*)x1, vs2, vq2, gv2, bv2, (float4*)xout);
}